// Round 7
// baseline (45812.076 us; speedup 1.0000x reference)
//
#include <hip/hip_runtime.h>

typedef _Float16 f16;
typedef _Float16 f16x4 __attribute__((ext_vector_type(4)));
typedef _Float16 f16x8 __attribute__((ext_vector_type(8)));
typedef float    f32x4 __attribute__((ext_vector_type(4)));

#define NN 1024
#define NT 12
#define NHOR 12
#define ROWS (NN*64)                      // 65536 (n*64+b)
#define MATH (1024*1024)
static const long SLOT = (long)NN*4096;   // diffusion slot [n][b*64+u] = 4M halves

__device__ __forceinline__ int sw4(int row){ return (row ^ (row>>2)) & 3; }

// interleave within each 32-window: chunk c holds k = [4c..4c+3, 16+4c..16+4c+3]
__device__ __forceinline__ int ilvpos(int k){
  int r = k & 31;
  return (k & ~31) + ((r & 12) << 1) + (r & 3) + ((r & 16) >> 2);
}

__device__ __forceinline__ void gld(const f16* g, f16* l){
  __builtin_amdgcn_global_load_lds((const __attribute__((address_space(1))) void*)g,
                                   (__attribute__((address_space(3))) void*)l, 16, 0, 0);
}

// ---- cell-kernel staging (64B rows, sw4 XOR), as in R3 ----
template<int NR>
__device__ __forceinline__ void stage(f16* lds, const f16* src, int ldk, int k0, int tid){
  #pragma unroll
  for (int ic=0; ic<NR/64; ++ic){
    const int c = tid + ic*256;
    const int row = c>>2, c4 = c&3;
    const f16* g = src + (long)row*ldk + k0 + ((c4 ^ sw4(row))<<3);
    gld(g, lds + c*8);
  }
}
__device__ __forceinline__ f16x8 fragI(const f16* lds, int row, int rq){
  return *(const f16x8*)&lds[row*32 + ((rq ^ sw4(row))<<3)];
}
__device__ __forceinline__ f16x8 fragN(const f16* lds, int row, int lk){
  const int s = sw4(row);
  const int cl = (lk>>3) ^ s, ch = (2|(lk>>3)) ^ s;
  f16x4 lo = *(const f16x4*)&lds[row*32 + (cl<<3) + (lk&7)];
  f16x4 hi = *(const f16x4*)&lds[row*32 + (ch<<3) + (lk&7)];
  f16x8 r; r[0]=lo[0];r[1]=lo[1];r[2]=lo[2];r[3]=lo[3];
  r[4]=hi[0];r[5]=hi[1];r[6]=hi[2];r[7]=hi[3];
  return r;
}

// ---------------------------------------------------------------- diffusion GEMM (256x256, pipelined)
// D[(q,n)][bu] = sum_m W[(q,n)][m] * Y[bu][m]; both operands ilv rows [.][1024].
// NOTE: no XCD swizzle — natural mapping pins W row-panels per XCD (rt%8) which is optimal here.
struct DiffP {
  const f16* W; const f16* Y0; const f16* Y1;
  f16* out0; f16* out1;
  int nct0; int mode_x; int wsq;
};

__global__ __launch_bounds__(512, 2) void gemm_diff(DiffP p) {
  __shared__ f16 L[4][16384];               // ring: W at +0 (256x32), Y at +8192
  const int tid=threadIdx.x, l=tid&63, w=tid>>6;
  const int ro=l&15, rq=l>>4;
  const int rt = blockIdx.x, ct = blockIdx.y;   // natural order (R6 swizzle removed)
  const int part = (ct >= p.nct0) ? 1 : 0;
  const int ctl  = part ? ct - p.nct0 : ct;
  const f16* Wb = p.W + (long)rt*(256*1024);
  const f16* Yb = (part ? p.Y1 : p.Y0) + (long)ctl*(256*1024);
  const int wm=(w>>2)*128, wc=(w&3)*64;
  // staging: thread handles chunks tid and tid+512 (row = c>>2, chunk = c&3)
  const int ca=tid, cb2=tid+512;
  const int ra=ca>>2, pa=ca&3, rb=cb2>>2, pb2=cb2&3;
  const long sa = (long)ra*1024 + ((pa ^ (ra&3))<<3);
  const long sb = (long)rb*1024 + ((pb2 ^ (rb&3))<<3);
  const int da = ra*32 + pa*8, db = rb*32 + pb2*8;
  f32x4 acc[8][4] = {};
  auto STAGE = [&](int tt){
    f16* Lr = L[tt&3]; const int k0 = tt*32;
    gld(Wb+k0+sa, Lr+da);      gld(Wb+k0+sb, Lr+db);
    gld(Yb+k0+sa, Lr+8192+da); gld(Yb+k0+sb, Lr+8192+db);
  };
  STAGE(0); STAGE(1);
  asm volatile("s_waitcnt vmcnt(4)" ::: "memory");
  __builtin_amdgcn_s_barrier();
  for (int t=0; t<32; ++t) {
    const f16* Lw = L[t&3];
    const f16* Ly = Lw + 8192;
    f16x8 wf[8], yf[4];
    #pragma unroll
    for (int i=0;i<8;i++){ const int r=wm+i*16+ro; wf[i]=*(const f16x8*)&Lw[r*32+((rq^(r&3))<<3)]; }
    #pragma unroll
    for (int j=0;j<4;j++){ const int r=wc+j*16+ro; yf[j]=*(const f16x8*)&Ly[r*32+((rq^(r&3))<<3)]; }
    if (t+2 < 32) STAGE(t+2);
    asm volatile("s_waitcnt lgkmcnt(0)" ::: "memory");
    __builtin_amdgcn_sched_barrier(0);
    __builtin_amdgcn_s_setprio(1);
    if (!p.wsq) {
      #pragma unroll
      for (int i=0;i<8;i++)
        #pragma unroll
        for (int j=0;j<4;j++)
          acc[i][j]=__builtin_amdgcn_mfma_f32_16x16x32_f16(wf[i],yf[j],acc[i][j],0,0,0);
    } else {
      #pragma unroll
      for (int i=0;i<8;i++)
        #pragma unroll
        for (int j=0;j<4;j++)
          acc[i][j]=__builtin_amdgcn_mfma_f32_16x16x32_f16(yf[j],wf[i],acc[i][j],0,0,0);
    }
    __builtin_amdgcn_s_setprio(0);
    if (t==31) break;
    if (t<29) { asm volatile("s_waitcnt vmcnt(4)" ::: "memory"); }
    else      { asm volatile("s_waitcnt vmcnt(0)" ::: "memory"); }
    __builtin_amdgcn_s_barrier();
  }
  if (p.wsq) {
    #pragma unroll
    for (int i=0;i<8;i++){
      const int n = rt*256 + wm + i*16 + ro;
      #pragma unroll
      for (int j=0;j<4;j++){
        const int m0 = ct*256 + wc + j*16 + rq*4;
        f16x4 sv;
        #pragma unroll
        for (int e=0;e<4;e++) sv[e] = (f16)(2.f*acc[i][j][e] - ((n==m0+e)?1.f:0.f));
        *(f16x4*)&p.out0[(long)n*1024 + m0] = sv;
      }
    }
    return;
  }
  f16* ob = part ? p.out1 : p.out0;
  const int mode = part ? p.mode_x : 0;
  #pragma unroll
  for (int i=0;i<8;i++){
    #pragma unroll
    for (int e=0;e<4;e++){
      const int c = rt*256 + wm + i*16 + rq*4 + e;   // global (q,n)
      const int q = c>>10, nn = c&1023;
      #pragma unroll
      for (int j=0;j<4;j++){
        const f16 v = (f16)acc[i][j][e];
        if (mode==0) {
          ob[(long)q*SLOT + (long)nn*4096 + (long)ctl*256 + wc + j*16 + ro] = v;
        } else {
          const int bul = wc + j*16 + ro;
          if (bul < 64) ob[(long)q*ROWS + nn*64 + bul] = v;
        }
      }
    }
  }
}

// ---------------------------------------------------------------- cell GEMMs (single-buffered)
struct Tab5 { const f16* p[5]; };
struct CellP {
  Tab5 ta, tb, xq;
  const f16 *wa, *wb, *wx0;   // wa/wb: [O][320] ilv; wx0: [5][O] natural
  const float* bias;
  const float* h32in;
  f16* rh; f16* rhhat; float* u32;
  float* h32io; f16* h16io; f16* hhat;
  int nseg, xf1;
};

template<int O, int GATE>
__global__ __launch_bounds__(256) void cell_gemm(CellP p) {
  constexpr int FC = O/32;
  __shared__ f16 As[128*32];
  __shared__ f16 Bs[O*32];
  const int tid=threadIdx.x, l=tid&63, w=tid>>6;
  const int rq=l>>4, ro=l&15, lk=rq*4;
  const int wm=(w>>1)*64, wc=(w&1)*(O/2);
  f32x4 acc[4][FC] = {};
  const long r0 = (long)blockIdx.x*128;
  const int Ktot = p.nseg*320;
  for (int kg=0; kg<Ktot; kg+=32) {
    const int seg = (kg>=320) ? 1 : 0;
    const int kk  = kg - seg*320;
    const int q = kk>>6, kq = kk&63;
    const f16* asrc = (seg ? p.tb.p[q] : p.ta.p[q]) + r0*64;
    const f16* wsrc = seg ? p.wb : p.wa;
    stage<128>(As, asrc, 64, kq, tid);
    stage<O>(Bs, wsrc, 320, kk, tid);
    __syncthreads();
    f16x8 a[4], b[FC];
    #pragma unroll
    for (int i=0;i<4;i++) a[i] = fragN(As, wm + i*16 + ro, lk);
    #pragma unroll
    for (int j=0;j<FC;j++) b[j] = fragI(Bs, wc + j*16 + ro, rq);
    #pragma unroll
    for (int i=0;i<4;i++)
      #pragma unroll
      for (int j=0;j<FC;j++)
        acc[i][j] = __builtin_amdgcn_mfma_f32_16x16x32_f16(a[i], b[j], acc[i][j], 0,0,0);
    __syncthreads();
  }
  #pragma unroll
  for (int i=0;i<4;i++) {
    #pragma unroll
    for (int e=0;e<4;e++) {
      const long rg = r0 + wm + i*16 + rq*4 + e;
      const int bb = (int)(rg & 63), nn2 = (int)(rg >> 6);
      const long hcol = (long)ilvpos(nn2);
      float xv[5];
      if (p.xf1) {
        #pragma unroll
        for (int q2=0;q2<5;q2++) xv[q2] = (float)p.xq.p[q2][rg];
      }
      #pragma unroll
      for (int j=0;j<FC;j++) {
        const int col = wc + j*16 + ro;
        float v = acc[i][j][e] + p.bias[col];
        if (p.xf1) {
          #pragma unroll
          for (int q2=0;q2<5;q2++) v += xv[q2] * (float)p.wx0[q2*O + col];
        }
        if (GATE) {
          const float s = 1.f/(1.f + __expf(-v));
          if (col < 64) {
            const float rhv = s * p.h32in[rg*64 + col];
            p.rh[rg*64 + col] = (f16)rhv;
            p.rhhat[((long)bb*64 + col)*1024 + hcol] = (f16)rhv;
          } else {
            p.u32[rg*64 + (col-64)] = s;
          }
        } else {
          const float cc = tanhf(v);
          const float u  = p.u32[rg*64 + col];
          const float h  = p.h32io[rg*64 + col];
          const float hn = u*h + (1.f-u)*cc;
          p.h32io[rg*64 + col] = hn;
          p.h16io[rg*64 + col] = (f16)hn;
          p.hhat[((long)bb*64 + col)*1024 + hcol] = (f16)hn;
        }
      }
    }
  }
}

// ---------------------------------------------------------------- setup kernels
__global__ __launch_bounds__(256) void k_transpose(const f16* in, f16* out, int R, int C) {
  __shared__ f16 T[64*66];
  const long rb = (long)blockIdx.x*64, cb = (long)blockIdx.y*64;
  const int t = threadIdx.x;
  #pragma unroll
  for (int it=0; it<2; ++it) {
    const int r = (t>>3) + it*32, c8 = (t&7)*8;
    f16x8 v = *(const f16x8*)(in + (rb+r)*C + cb + c8);
    *(f16x8*)&T[r*66 + c8] = v;
  }
  __syncthreads();
  #pragma unroll
  for (int it=0; it<2; ++it) {
    const int c = (t>>3) + it*32, r8 = (t&7)*8;
    f16x8 v;
    #pragma unroll
    for (int j=0;j<8;j++) v[j] = T[(r8+j)*66 + c];
    *(f16x8*)(out + (cb+c)*R + rb + r8) = v;
  }
}

__global__ void k_cast_sup(const float* s, f16* o) {
  long i = (long)blockIdx.x*256 + threadIdx.x;
  if (i < 2LL*MATH) o[i] = (f16)s[i];
}

__global__ void k_ilv(const f16* in, f16* out) {
  int i = blockIdx.x*256 + threadIdx.x;
  if (i >= MATH) return;
  int r = i>>10, k = i&1023;
  out[(long)r*1024 + ilvpos(k)] = in[i];
}

__global__ void k_pack_x(const float* in, f16* xe, f16* xet) {
  int i = blockIdx.x*256 + threadIdx.x;
  if (i >= NT*ROWS) return;
  int t = i / ROWS, r = i % ROWS, n = r>>6, b = r&63;
  float v = in[(long)b*NN*NT + (long)n*NT + t];
  xe[i] = (f16)v;
  xet[(long)t*262144 + (long)b*1024 + ilvpos(n)] = (f16)v;
}

__global__ void k_split_w_t(const float* src, f16* wh_t, f16* wxA, int f, int xf, int O) {
  int i = blockIdx.x*256 + threadIdx.x;
  if (i >= 5*f*O) return;
  int o = i % O, rr = i / O, q = rr / f, ff = rr % f;
  f16 v = (f16)src[i];
  if (ff < xf) {
    if (xf == 1) wxA[q*O + o] = v;
    else         wxA[(long)o*320 + q*64 + ilvpos(ff)] = v;
  } else {
    wh_t[(long)o*320 + q*64 + ilvpos(ff - xf)] = v;
  }
}

__global__ void k_proj(const float* h32, const float* pw, const float* pb,
                       float* out, f16* xdec, f16* xdect) {
  int r = blockIdx.x*256 + threadIdx.x;
  if (r >= ROWS) return;
  float acc = pb[0];
  const float* hp = h32 + (long)r*64;
  #pragma unroll
  for (int k=0;k<64;k++) acc += hp[k]*pw[k];
  int n = r>>6, b = r&63;
  out[(long)b*NN + n] = acc;
  xdec[r] = (f16)acc;
  xdect[(long)b*1024 + ilvpos(n)] = (f16)acc;
}

// ---------------------------------------------------------------- driver
extern "C" void kernel_launch(void* const* d_in, const int* in_sizes, int n_in,
                              void* d_out, int out_size, void* d_ws, size_t ws_size,
                              hipStream_t stream) {
  (void)in_sizes; (void)n_in; (void)out_size; (void)ws_size;
  const float* inputs = (const float*)d_in[0];
  const float* sup    = (const float*)d_in[1];
  const float* gwp[4] = {(const float*)d_in[2], (const float*)d_in[6], (const float*)d_in[10], (const float*)d_in[14]};
  const float* gbp[4] = {(const float*)d_in[3], (const float*)d_in[7], (const float*)d_in[11], (const float*)d_in[15]};
  const float* cwp[4] = {(const float*)d_in[4], (const float*)d_in[8], (const float*)d_in[12], (const float*)d_in[16]};
  const float* cbp[4] = {(const float*)d_in[5], (const float*)d_in[9], (const float*)d_in[13], (const float*)d_in[17]};
  const float* pw = (const float*)d_in[18];
  const float* pb = (const float*)d_in[19];
  float* out = (float*)d_out;

  char* base = (char*)d_ws; size_t off = 0;
  auto alloc = [&](size_t bytes)->void* { void* p = base + off; off += (bytes + 255) & ~(size_t)255; return p; };
  f16* W16int = (f16*)alloc(4LL*MATH*2);         // [A0, 2A0^2-I, A1, 2A1^2-I] ilv rows
  f16* xenc   = (f16*)alloc((long)NT*ROWS*2);
  f16* xet    = (f16*)alloc((long)NT*262144*2);  // [t][256 row-pad][1024 n-ilv]
  f16* xdec   = (f16*)alloc((long)ROWS*2);
  f16* xdect  = (f16*)alloc(262144L*2);
  f16*  h16[2]  = {(f16*)alloc((long)ROWS*64*2),  (f16*)alloc((long)ROWS*64*2)};
  f16*  hh[2]   = {(f16*)alloc(4096L*1024*2),     (f16*)alloc(4096L*1024*2)};
  float* h32[2] = {(float*)alloc((long)ROWS*64*4), (float*)alloc((long)ROWS*64*4)};
  float* u32 = (float*)alloc((long)ROWS*64*4);
  f16* rh    = (f16*)alloc((long)ROWS*64*2);
  f16* rhh   = (f16*)alloc(4096L*1024*2);
  f16* Dh    = (f16*)alloc(4*SLOT*2);
  f16* Dx    = (f16*)alloc(4*SLOT*2);
  f16* Dx0   = (f16*)alloc(4LL*ROWS*2);
  f16 *gwh[4], *gwx[4], *cwh[4], *cwx[4];
  for (int i=0;i<4;i++) {
    gwh[i]=(f16*)alloc(128L*320*2); gwx[i]=(f16*)alloc(128L*320*2);
    cwh[i]=(f16*)alloc(64L*320*2);  cwx[i]=(f16*)alloc(64L*320*2);
  }

  hipMemsetAsync(h16[0], 0, (long)ROWS*64*2, stream);
  hipMemsetAsync(h16[1], 0, (long)ROWS*64*2, stream);
  hipMemsetAsync(hh[0],  0, 4096L*1024*2, stream);
  hipMemsetAsync(hh[1],  0, 4096L*1024*2, stream);
  hipMemsetAsync(h32[0], 0, (long)ROWS*64*4, stream);
  hipMemsetAsync(h32[1], 0, (long)ROWS*64*4, stream);
  hipMemsetAsync(xdec,   0, (long)ROWS*2, stream);
  hipMemsetAsync(xdect,  0, 262144L*2, stream);
  hipMemsetAsync(xet,    0, (long)NT*262144*2, stream);

  // setup: W16int[2s] = ilv(A_s); W16int[2s+1] = ilv(2*A_s^2 - I)
  f16* tmpA   = Dh;
  f16* tmpAt  = Dh + 2L*MATH;
  f16* tmpAti = Dh + 4L*MATH;
  f16* tmpSq  = Dh + 5L*MATH;
  k_cast_sup<<<(2*MATH+255)/256, 256, 0, stream>>>(sup, tmpA);
  for (int s=0;s<2;s++) {
    k_transpose<<<dim3(16,16),256,0,stream>>>(tmpA + (long)s*MATH, tmpAt + (long)s*MATH, 1024, 1024);
    k_ilv<<<4096,256,0,stream>>>(tmpA + (long)s*MATH, W16int + (long)(2*s)*MATH);
  }
  for (int s=0;s<2;s++) {
    k_ilv<<<4096,256,0,stream>>>(tmpAt + (long)s*MATH, tmpAti);
    DiffP mp{};
    mp.W = W16int + (long)(2*s)*MATH; mp.Y0 = tmpAti; mp.Y1 = tmpAti;
    mp.out0 = tmpSq; mp.nct0 = 4; mp.wsq = 1;
    gemm_diff<<<dim3(4,4),512,0,stream>>>(mp);
    k_ilv<<<4096,256,0,stream>>>(tmpSq, W16int + (long)(2*s+1)*MATH);
  }
  k_pack_x<<<(NT*ROWS+255)/256,256,0,stream>>>(inputs, xenc, xet);
  const int fs[4]  = {65,128,65,128};
  const int xfs[4] = {1,64,1,64};
  for (int i=0;i<4;i++) {
    k_split_w_t<<<(5*fs[i]*128+255)/256,256,0,stream>>>(gwp[i], gwh[i], gwx[i], fs[i], xfs[i], 128);
    k_split_w_t<<<(5*fs[i]*64 +255)/256,256,0,stream>>>(cwp[i], cwh[i], cwx[i], fs[i], xfs[i], 64);
  }

  auto run_cell = [&](const f16* xraw, const f16* xhat, int xf,
                      f16* h16c, f16* hhatc, float* h32c, int wi) {
    // diffusion of h (+x)
    DiffP dp{};
    dp.W = W16int; dp.Y0 = hhatc; dp.out0 = Dh; dp.nct0 = 16; dp.wsq = 0;
    int gy;
    if (xf == 64) { dp.Y1 = xhat; dp.out1 = Dx;  dp.mode_x = 0; gy = 32; }
    else          { dp.Y1 = xhat; dp.out1 = Dx0; dp.mode_x = 2; gy = 17; }
    gemm_diff<<<dim3(16, gy), 512, 0, stream>>>(dp);
    // gate
    CellP gp{};
    gp.ta.p[0] = h16c; for (int q=1;q<5;q++) gp.ta.p[q] = Dh + (long)(q-1)*SLOT;
    gp.wa = gwh[wi]; gp.bias = gbp[wi];
    gp.h32in = h32c; gp.rh = rh; gp.rhhat = rhh; gp.u32 = u32;
    if (xf == 64) {
      gp.nseg = 2; gp.xf1 = 0;
      gp.tb.p[0] = xraw; for (int q=1;q<5;q++) gp.tb.p[q] = Dx + (long)(q-1)*SLOT;
      gp.wb = gwx[wi];
    } else {
      gp.nseg = 1; gp.xf1 = 1;
      gp.xq.p[0] = xraw; for (int q=1;q<5;q++) gp.xq.p[q] = Dx0 + (long)(q-1)*ROWS;
      gp.wx0 = gwx[wi];
    }
    cell_gemm<128,1><<<512, 256, 0, stream>>>(gp);
    // diffusion of rh
    DiffP dp2{};
    dp2.W = W16int; dp2.Y0 = rhh; dp2.Y1 = rhh; dp2.out0 = Dh; dp2.nct0 = 16; dp2.wsq = 0;
    gemm_diff<<<dim3(16, 16), 512, 0, stream>>>(dp2);
    // candidate + GRU update
    CellP cp{};
    cp.ta.p[0] = rh; for (int q=1;q<5;q++) cp.ta.p[q] = Dh + (long)(q-1)*SLOT;
    cp.wa = cwh[wi]; cp.bias = cbp[wi];
    cp.u32 = u32; cp.h32io = h32c; cp.h16io = h16c; cp.hhat = hhatc;
    if (xf == 64) {
      cp.nseg = 2; cp.xf1 = 0;
      cp.tb.p[0] = xraw; for (int q=1;q<5;q++) cp.tb.p[q] = Dx + (long)(q-1)*SLOT;
      cp.wb = cwx[wi];
    } else {
      cp.nseg = 1; cp.xf1 = 1;
      cp.xq.p[0] = xraw; for (int q=1;q<5;q++) cp.xq.p[q] = Dx0 + (long)(q-1)*ROWS;
      cp.wx0 = cwx[wi];
    }
    cell_gemm<64,0><<<512, 256, 0, stream>>>(cp);
  };

  for (int t=0;t<NT;t++) {
    run_cell(xenc + (long)t*ROWS, xet + (long)t*262144, 1, h16[0], hh[0], h32[0], 0);
    run_cell(h16[0], hh[0],                            64, h16[1], hh[1], h32[1], 1);
  }
  for (int s=0;s<NHOR;s++) {
    run_cell(xdec,   xdect,   1, h16[0], hh[0], h32[0], 2);
    run_cell(h16[0], hh[0],  64, h16[1], hh[1], h32[1], 3);
    k_proj<<<ROWS/256, 256, 0, stream>>>(h32[1], pw, pb, out + (long)s*ROWS, xdec, xdect);
  }
}

// Round 8
// 26924.429 us; speedup vs baseline: 1.7015x; 1.7015x over previous
//
#include <hip/hip_runtime.h>

typedef _Float16 f16;
typedef _Float16 f16x4 __attribute__((ext_vector_type(4)));
typedef _Float16 f16x8 __attribute__((ext_vector_type(8)));
typedef float    f32x4 __attribute__((ext_vector_type(4)));

#define NN 1024
#define NT 12
#define NHOR 12
#define ROWS (NN*64)                      // 65536 (n*64+b)
#define MATH (1024*1024)
static const long SLOT = (long)NN*4096;   // diffusion slot [n][b*64+u] = 4M halves

__device__ __forceinline__ int sw4(int row){ return (row ^ (row>>2)) & 3; }

// interleave within each 32-window: chunk c holds k = [4c..4c+3, 16+4c..16+4c+3]
__device__ __forceinline__ int ilvpos(int k){
  int r = k & 31;
  return (k & ~31) + ((r & 12) << 1) + (r & 3) + ((r & 16) >> 2);
}

__device__ __forceinline__ void gld(const f16* g, f16* l){
  __builtin_amdgcn_global_load_lds((const __attribute__((address_space(1))) void*)g,
                                   (__attribute__((address_space(3))) void*)l, 16, 0, 0);
}

// ---- cell-kernel staging (64B rows, sw4 XOR), as in R3 ----
template<int NR>
__device__ __forceinline__ void stage(f16* lds, const f16* src, int ldk, int k0, int tid){
  #pragma unroll
  for (int ic=0; ic<NR/64; ++ic){
    const int c = tid + ic*256;
    const int row = c>>2, c4 = c&3;
    const f16* g = src + (long)row*ldk + k0 + ((c4 ^ sw4(row))<<3);
    gld(g, lds + c*8);
  }
}
__device__ __forceinline__ f16x8 fragI(const f16* lds, int row, int rq){
  return *(const f16x8*)&lds[row*32 + ((rq ^ sw4(row))<<3)];
}
__device__ __forceinline__ f16x8 fragN(const f16* lds, int row, int lk){
  const int s = sw4(row);
  const int cl = (lk>>3) ^ s, ch = (2|(lk>>3)) ^ s;
  f16x4 lo = *(const f16x4*)&lds[row*32 + (cl<<3) + (lk&7)];
  f16x4 hi = *(const f16x4*)&lds[row*32 + (ch<<3) + (lk&7)];
  f16x8 r; r[0]=lo[0];r[1]=lo[1];r[2]=lo[2];r[3]=lo[3];
  r[4]=hi[0];r[5]=hi[1];r[6]=hi[2];r[7]=hi[3];
  return r;
}

// ---------------------------------------------------------------- diffusion GEMM (256x256, pipelined)
// D[(q,n)][bu] = sum_m W[(q,n)][m] * Y[bu][m]; both operands ilv rows [.][1024].
struct DiffP {
  const f16* W; const f16* Y0; const f16* Y1;
  f16* out0; f16* out1;
  int nct0; int mode_x; int wsq;
};

__global__ __launch_bounds__(512) void gemm_diff(DiffP p) {
  __shared__ f16 L[4][16384];               // ring: W at +0 (256x32), Y at +8192
  const int tid=threadIdx.x, l=tid&63, w=tid>>6;
  const int ro=l&15, rq=l>>4;
  const int rt = blockIdx.x, ct = blockIdx.y;
  const int part = (ct >= p.nct0) ? 1 : 0;
  const int ctl  = part ? ct - p.nct0 : ct;
  const f16* Wb = p.W + (long)rt*(256*1024);
  const f16* Yb = (part ? p.Y1 : p.Y0) + (long)ctl*(256*1024);
  const int wm=(w>>2)*128, wc=(w&3)*64;
  // staging: thread handles chunks tid and tid+512 (row = c>>2, chunk = c&3)
  const int ca=tid, cb2=tid+512;
  const int ra=ca>>2, pa=ca&3, rb=cb2>>2, pb2=cb2&3;
  const long sa = (long)ra*1024 + ((pa ^ (ra&3))<<3);
  const long sb = (long)rb*1024 + ((pb2 ^ (rb&3))<<3);
  const int da = ra*32 + pa*8, db = rb*32 + pb2*8;
  f32x4 acc[8][4] = {};
  auto STAGE = [&](int tt){
    f16* Lr = L[tt&3]; const int k0 = tt*32;
    gld(Wb+k0+sa, Lr+da);      gld(Wb+k0+sb, Lr+db);
    gld(Yb+k0+sa, Lr+8192+da); gld(Yb+k0+sb, Lr+8192+db);
  };
  STAGE(0); STAGE(1);
  asm volatile("s_waitcnt vmcnt(4)" ::: "memory");
  __builtin_amdgcn_s_barrier();
  __builtin_amdgcn_sched_barrier(0);
  for (int t=0; t<32; ++t) {
    const f16* Lw = L[t&3];
    const f16* Ly = Lw + 8192;
    if (t+2 < 32) STAGE(t+2);
    f16x8 yf[4];
    #pragma unroll
    for (int j=0;j<4;j++){ const int r=wc+j*16+ro; yf[j]=*(const f16x8*)&Ly[r*32+((rq^(r&3))<<3)]; }
    __builtin_amdgcn_s_setprio(1);
    if (!p.wsq) {
      #pragma unroll
      for (int i=0;i<8;i++){
        const int r=wm+i*16+ro;
        const f16x8 wfi = *(const f16x8*)&Lw[r*32+((rq^(r&3))<<3)];
        #pragma unroll
        for (int j=0;j<4;j++)
          acc[i][j]=__builtin_amdgcn_mfma_f32_16x16x32_f16(wfi,yf[j],acc[i][j],0,0,0);
      }
    } else {
      #pragma unroll
      for (int i=0;i<8;i++){
        const int r=wm+i*16+ro;
        const f16x8 wfi = *(const f16x8*)&Lw[r*32+((rq^(r&3))<<3)];
        #pragma unroll
        for (int j=0;j<4;j++)
          acc[i][j]=__builtin_amdgcn_mfma_f32_16x16x32_f16(yf[j],wfi,acc[i][j],0,0,0);
      }
    }
    __builtin_amdgcn_s_setprio(0);
    if (t==31) break;
    if (t<29) { asm volatile("s_waitcnt vmcnt(4)" ::: "memory"); }
    else      { asm volatile("s_waitcnt vmcnt(0)" ::: "memory"); }
    __builtin_amdgcn_s_barrier();
    __builtin_amdgcn_sched_barrier(0);
  }
  if (p.wsq) {
    #pragma unroll
    for (int i=0;i<8;i++){
      const int n = rt*256 + wm + i*16 + ro;
      #pragma unroll
      for (int j=0;j<4;j++){
        const int m0 = ct*256 + wc + j*16 + rq*4;
        f16x4 sv;
        #pragma unroll
        for (int e=0;e<4;e++) sv[e] = (f16)(2.f*acc[i][j][e] - ((n==m0+e)?1.f:0.f));
        *(f16x4*)&p.out0[(long)n*1024 + m0] = sv;
      }
    }
    return;
  }
  f16* ob = part ? p.out1 : p.out0;
  const int mode = part ? p.mode_x : 0;
  #pragma unroll
  for (int i=0;i<8;i++){
    #pragma unroll
    for (int e=0;e<4;e++){
      const int c = rt*256 + wm + i*16 + rq*4 + e;   // global (q,n)
      const int q = c>>10, nn = c&1023;
      #pragma unroll
      for (int j=0;j<4;j++){
        const f16 v = (f16)acc[i][j][e];
        if (mode==0) {
          ob[(long)q*SLOT + (long)nn*4096 + (long)ctl*256 + wc + j*16 + ro] = v;
        } else {
          const int bul = wc + j*16 + ro;
          if (bul < 64) ob[(long)q*ROWS + nn*64 + bul] = v;
        }
      }
    }
  }
}

// ---------------------------------------------------------------- cell GEMMs (single-buffered)
struct Tab5 { const f16* p[5]; };
struct CellP {
  Tab5 ta, tb, xq;
  const f16 *wa, *wb, *wx0;   // wa/wb: [O][320] ilv; wx0: [5][O] natural
  const float* bias;
  const float* h32in;
  f16* rh; f16* rhhat; float* u32;
  float* h32io; f16* h16io; f16* hhat;
  int nseg, xf1;
};

template<int O, int GATE>
__global__ __launch_bounds__(256) void cell_gemm(CellP p) {
  constexpr int FC = O/32;
  __shared__ f16 As[128*32];
  __shared__ f16 Bs[O*32];
  const int tid=threadIdx.x, l=tid&63, w=tid>>6;
  const int rq=l>>4, ro=l&15, lk=rq*4;
  const int wm=(w>>1)*64, wc=(w&1)*(O/2);
  f32x4 acc[4][FC] = {};
  const long r0 = (long)blockIdx.x*128;
  const int Ktot = p.nseg*320;
  for (int kg=0; kg<Ktot; kg+=32) {
    const int seg = (kg>=320) ? 1 : 0;
    const int kk  = kg - seg*320;
    const int q = kk>>6, kq = kk&63;
    const f16* asrc = (seg ? p.tb.p[q] : p.ta.p[q]) + r0*64;
    const f16* wsrc = seg ? p.wb : p.wa;
    stage<128>(As, asrc, 64, kq, tid);
    stage<O>(Bs, wsrc, 320, kk, tid);
    __syncthreads();
    f16x8 a[4], b[FC];
    #pragma unroll
    for (int i=0;i<4;i++) a[i] = fragN(As, wm + i*16 + ro, lk);
    #pragma unroll
    for (int j=0;j<FC;j++) b[j] = fragI(Bs, wc + j*16 + ro, rq);
    #pragma unroll
    for (int i=0;i<4;i++)
      #pragma unroll
      for (int j=0;j<FC;j++)
        acc[i][j] = __builtin_amdgcn_mfma_f32_16x16x32_f16(a[i], b[j], acc[i][j], 0,0,0);
    __syncthreads();
  }
  #pragma unroll
  for (int i=0;i<4;i++) {
    #pragma unroll
    for (int e=0;e<4;e++) {
      const long rg = r0 + wm + i*16 + rq*4 + e;
      const int bb = (int)(rg & 63), nn2 = (int)(rg >> 6);
      const long hcol = (long)ilvpos(nn2);
      float xv[5];
      if (p.xf1) {
        #pragma unroll
        for (int q2=0;q2<5;q2++) xv[q2] = (float)p.xq.p[q2][rg];
      }
      #pragma unroll
      for (int j=0;j<FC;j++) {
        const int col = wc + j*16 + ro;
        float v = acc[i][j][e] + p.bias[col];
        if (p.xf1) {
          #pragma unroll
          for (int q2=0;q2<5;q2++) v += xv[q2] * (float)p.wx0[q2*O + col];
        }
        if (GATE) {
          const float s = 1.f/(1.f + __expf(-v));
          if (col < 64) {
            const float rhv = s * p.h32in[rg*64 + col];
            p.rh[rg*64 + col] = (f16)rhv;
            p.rhhat[((long)bb*64 + col)*1024 + hcol] = (f16)rhv;
          } else {
            p.u32[rg*64 + (col-64)] = s;
          }
        } else {
          const float cc = tanhf(v);
          const float u  = p.u32[rg*64 + col];
          const float h  = p.h32io[rg*64 + col];
          const float hn = u*h + (1.f-u)*cc;
          p.h32io[rg*64 + col] = hn;
          p.h16io[rg*64 + col] = (f16)hn;
          p.hhat[((long)bb*64 + col)*1024 + hcol] = (f16)hn;
        }
      }
    }
  }
}

// ---------------------------------------------------------------- setup kernels
__global__ __launch_bounds__(256) void k_transpose(const f16* in, f16* out, int R, int C) {
  __shared__ f16 T[64*66];
  const long rb = (long)blockIdx.x*64, cb = (long)blockIdx.y*64;
  const int t = threadIdx.x;
  #pragma unroll
  for (int it=0; it<2; ++it) {
    const int r = (t>>3) + it*32, c8 = (t&7)*8;
    f16x8 v = *(const f16x8*)(in + (rb+r)*C + cb + c8);
    *(f16x8*)&T[r*66 + c8] = v;
  }
  __syncthreads();
  #pragma unroll
  for (int it=0; it<2; ++it) {
    const int c = (t>>3) + it*32, r8 = (t&7)*8;
    f16x8 v;
    #pragma unroll
    for (int j=0;j<8;j++) v[j] = T[(r8+j)*66 + c];
    *(f16x8*)(out + (cb+c)*R + rb + r8) = v;
  }
}

__global__ void k_cast_sup(const float* s, f16* o) {
  long i = (long)blockIdx.x*256 + threadIdx.x;
  if (i < 2LL*MATH) o[i] = (f16)s[i];
}

__global__ void k_ilv(const f16* in, f16* out) {
  int i = blockIdx.x*256 + threadIdx.x;
  if (i >= MATH) return;
  int r = i>>10, k = i&1023;
  out[(long)r*1024 + ilvpos(k)] = in[i];
}

__global__ void k_pack_x(const float* in, f16* xe, f16* xet) {
  int i = blockIdx.x*256 + threadIdx.x;
  if (i >= NT*ROWS) return;
  int t = i / ROWS, r = i % ROWS, n = r>>6, b = r&63;
  float v = in[(long)b*NN*NT + (long)n*NT + t];
  xe[i] = (f16)v;
  xet[(long)t*262144 + (long)b*1024 + ilvpos(n)] = (f16)v;
}

__global__ void k_split_w_t(const float* src, f16* wh_t, f16* wxA, int f, int xf, int O) {
  int i = blockIdx.x*256 + threadIdx.x;
  if (i >= 5*f*O) return;
  int o = i % O, rr = i / O, q = rr / f, ff = rr % f;
  f16 v = (f16)src[i];
  if (ff < xf) {
    if (xf == 1) wxA[q*O + o] = v;
    else         wxA[(long)o*320 + q*64 + ilvpos(ff)] = v;
  } else {
    wh_t[(long)o*320 + q*64 + ilvpos(ff - xf)] = v;
  }
}

__global__ void k_proj(const float* h32, const float* pw, const float* pb,
                       float* out, f16* xdec, f16* xdect) {
  int r = blockIdx.x*256 + threadIdx.x;
  if (r >= ROWS) return;
  float acc = pb[0];
  const float* hp = h32 + (long)r*64;
  #pragma unroll
  for (int k=0;k<64;k++) acc += hp[k]*pw[k];
  int n = r>>6, b = r&63;
  out[(long)b*NN + n] = acc;
  xdec[r] = (f16)acc;
  xdect[(long)b*1024 + ilvpos(n)] = (f16)acc;
}

// ---------------------------------------------------------------- driver
extern "C" void kernel_launch(void* const* d_in, const int* in_sizes, int n_in,
                              void* d_out, int out_size, void* d_ws, size_t ws_size,
                              hipStream_t stream) {
  (void)in_sizes; (void)n_in; (void)out_size; (void)ws_size;
  const float* inputs = (const float*)d_in[0];
  const float* sup    = (const float*)d_in[1];
  const float* gwp[4] = {(const float*)d_in[2], (const float*)d_in[6], (const float*)d_in[10], (const float*)d_in[14]};
  const float* gbp[4] = {(const float*)d_in[3], (const float*)d_in[7], (const float*)d_in[11], (const float*)d_in[15]};
  const float* cwp[4] = {(const float*)d_in[4], (const float*)d_in[8], (const float*)d_in[12], (const float*)d_in[16]};
  const float* cbp[4] = {(const float*)d_in[5], (const float*)d_in[9], (const float*)d_in[13], (const float*)d_in[17]};
  const float* pw = (const float*)d_in[18];
  const float* pb = (const float*)d_in[19];
  float* out = (float*)d_out;

  char* base = (char*)d_ws; size_t off = 0;
  auto alloc = [&](size_t bytes)->void* { void* p = base + off; off += (bytes + 255) & ~(size_t)255; return p; };
  f16* W16int = (f16*)alloc(4LL*MATH*2);         // [A0, 2A0^2-I, A1, 2A1^2-I] ilv rows
  f16* xenc   = (f16*)alloc((long)NT*ROWS*2);
  f16* xet    = (f16*)alloc((long)NT*262144*2);  // [t][256 row-pad][1024 n-ilv]
  f16* xdec   = (f16*)alloc((long)ROWS*2);
  f16* xdect  = (f16*)alloc(262144L*2);
  f16*  h16[2]  = {(f16*)alloc((long)ROWS*64*2),  (f16*)alloc((long)ROWS*64*2)};
  f16*  hh[2]   = {(f16*)alloc(4096L*1024*2),     (f16*)alloc(4096L*1024*2)};
  float* h32[2] = {(float*)alloc((long)ROWS*64*4), (float*)alloc((long)ROWS*64*4)};
  float* u32 = (float*)alloc((long)ROWS*64*4);
  f16* rh    = (f16*)alloc((long)ROWS*64*2);
  f16* rhh   = (f16*)alloc(4096L*1024*2);
  f16* Dh    = (f16*)alloc(4*SLOT*2);
  f16* Dx    = (f16*)alloc(4*SLOT*2);
  f16* Dx0   = (f16*)alloc(4LL*ROWS*2);
  f16 *gwh[4], *gwx[4], *cwh[4], *cwx[4];
  for (int i=0;i<4;i++) {
    gwh[i]=(f16*)alloc(128L*320*2); gwx[i]=(f16*)alloc(128L*320*2);
    cwh[i]=(f16*)alloc(64L*320*2);  cwx[i]=(f16*)alloc(64L*320*2);
  }

  hipMemsetAsync(h16[0], 0, (long)ROWS*64*2, stream);
  hipMemsetAsync(h16[1], 0, (long)ROWS*64*2, stream);
  hipMemsetAsync(hh[0],  0, 4096L*1024*2, stream);
  hipMemsetAsync(hh[1],  0, 4096L*1024*2, stream);
  hipMemsetAsync(h32[0], 0, (long)ROWS*64*4, stream);
  hipMemsetAsync(h32[1], 0, (long)ROWS*64*4, stream);
  hipMemsetAsync(xdec,   0, (long)ROWS*2, stream);
  hipMemsetAsync(xdect,  0, 262144L*2, stream);
  hipMemsetAsync(xet,    0, (long)NT*262144*2, stream);

  // setup: W16int[2s] = ilv(A_s); W16int[2s+1] = ilv(2*A_s^2 - I)
  f16* tmpA   = Dh;
  f16* tmpAt  = Dh + 2L*MATH;
  f16* tmpAti = Dh + 4L*MATH;
  f16* tmpSq  = Dh + 5L*MATH;
  k_cast_sup<<<(2*MATH+255)/256, 256, 0, stream>>>(sup, tmpA);
  for (int s=0;s<2;s++) {
    k_transpose<<<dim3(16,16),256,0,stream>>>(tmpA + (long)s*MATH, tmpAt + (long)s*MATH, 1024, 1024);
    k_ilv<<<4096,256,0,stream>>>(tmpA + (long)s*MATH, W16int + (long)(2*s)*MATH);
  }
  for (int s=0;s<2;s++) {
    k_ilv<<<4096,256,0,stream>>>(tmpAt + (long)s*MATH, tmpAti);
    DiffP mp{};
    mp.W = W16int + (long)(2*s)*MATH; mp.Y0 = tmpAti; mp.Y1 = tmpAti;
    mp.out0 = tmpSq; mp.nct0 = 4; mp.wsq = 1;
    gemm_diff<<<dim3(4,4),512,0,stream>>>(mp);
    k_ilv<<<4096,256,0,stream>>>(tmpSq, W16int + (long)(2*s+1)*MATH);
  }
  k_pack_x<<<(NT*ROWS+255)/256,256,0,stream>>>(inputs, xenc, xet);
  const int fs[4]  = {65,128,65,128};
  const int xfs[4] = {1,64,1,64};
  for (int i=0;i<4;i++) {
    k_split_w_t<<<(5*fs[i]*128+255)/256,256,0,stream>>>(gwp[i], gwh[i], gwx[i], fs[i], xfs[i], 128);
    k_split_w_t<<<(5*fs[i]*64 +255)/256,256,0,stream>>>(cwp[i], cwh[i], cwx[i], fs[i], xfs[i], 64);
  }

  auto run_cell = [&](const f16* xraw, const f16* xhat, int xf,
                      f16* h16c, f16* hhatc, float* h32c, int wi) {
    // diffusion of h (+x)
    DiffP dp{};
    dp.W = W16int; dp.Y0 = hhatc; dp.out0 = Dh; dp.nct0 = 16; dp.wsq = 0;
    int gy;
    if (xf == 64) { dp.Y1 = xhat; dp.out1 = Dx;  dp.mode_x = 0; gy = 32; }
    else          { dp.Y1 = xhat; dp.out1 = Dx0; dp.mode_x = 2; gy = 17; }
    gemm_diff<<<dim3(16, gy), 512, 0, stream>>>(dp);
    // gate
    CellP gp{};
    gp.ta.p[0] = h16c; for (int q=1;q<5;q++) gp.ta.p[q] = Dh + (long)(q-1)*SLOT;
    gp.wa = gwh[wi]; gp.bias = gbp[wi];
    gp.h32in = h32c; gp.rh = rh; gp.rhhat = rhh; gp.u32 = u32;
    if (xf == 64) {
      gp.nseg = 2; gp.xf1 = 0;
      gp.tb.p[0] = xraw; for (int q=1;q<5;q++) gp.tb.p[q] = Dx + (long)(q-1)*SLOT;
      gp.wb = gwx[wi];
    } else {
      gp.nseg = 1; gp.xf1 = 1;
      gp.xq.p[0] = xraw; for (int q=1;q<5;q++) gp.xq.p[q] = Dx0 + (long)(q-1)*ROWS;
      gp.wx0 = gwx[wi];
    }
    cell_gemm<128,1><<<512, 256, 0, stream>>>(gp);
    // diffusion of rh
    DiffP dp2{};
    dp2.W = W16int; dp2.Y0 = rhh; dp2.Y1 = rhh; dp2.out0 = Dh; dp2.nct0 = 16; dp2.wsq = 0;
    gemm_diff<<<dim3(16, 16), 512, 0, stream>>>(dp2);
    // candidate + GRU update
    CellP cp{};
    cp.ta.p[0] = rh; for (int q=1;q<5;q++) cp.ta.p[q] = Dh + (long)(q-1)*SLOT;
    cp.wa = cwh[wi]; cp.bias = cbp[wi];
    cp.u32 = u32; cp.h32io = h32c; cp.h16io = h16c; cp.hhat = hhatc;
    if (xf == 64) {
      cp.nseg = 2; cp.xf1 = 0;
      cp.tb.p[0] = xraw; for (int q=1;q<5;q++) cp.tb.p[q] = Dx + (long)(q-1)*SLOT;
      cp.wb = cwx[wi];
    } else {
      cp.nseg = 1; cp.xf1 = 1;
      cp.xq.p[0] = xraw; for (int q=1;q<5;q++) cp.xq.p[q] = Dx0 + (long)(q-1)*ROWS;
      cp.wx0 = cwx[wi];
    }
    cell_gemm<64,0><<<512, 256, 0, stream>>>(cp);
  };

  for (int t=0;t<NT;t++) {
    run_cell(xenc + (long)t*ROWS, xet + (long)t*262144, 1, h16[0], hh[0], h32[0], 0);
    run_cell(h16[0], hh[0],                            64, h16[1], hh[1], h32[1], 1);
  }
  for (int s=0;s<NHOR;s++) {
    run_cell(xdec,   xdect,   1, h16[0], hh[0], h32[0], 2);
    run_cell(h16[0], hh[0],  64, h16[1], hh[1], h32[1], 3);
    k_proj<<<ROWS/256, 256, 0, stream>>>(h32[1], pw, pb, out + (long)s*ROWS, xdec, xdect);
  }
}

// Round 9
// 11951.318 us; speedup vs baseline: 3.8332x; 2.2528x over previous
//
#include <hip/hip_runtime.h>

typedef _Float16 f16;
typedef _Float16 f16x4 __attribute__((ext_vector_type(4)));
typedef _Float16 f16x8 __attribute__((ext_vector_type(8)));
typedef float    f32x4 __attribute__((ext_vector_type(4)));

#define NN 1024
#define NT 12
#define NHOR 12
#define ROWS (NN*64)                      // 65536 (n*64+b)
#define MATH (1024*1024)
static const long SLOT = (long)NN*4096;   // diffusion slot [n][b*64+u] = 4M halves

__device__ __forceinline__ int sw4(int row){ return (row ^ (row>>2)) & 3; }

// interleave within each 32-window: chunk c holds k = [4c..4c+3, 16+4c..16+4c+3]
__device__ __forceinline__ int ilvpos(int k){
  int r = k & 31;
  return (k & ~31) + ((r & 12) << 1) + (r & 3) + ((r & 16) >> 2);
}

__device__ __forceinline__ void gld(const f16* g, f16* l){
  __builtin_amdgcn_global_load_lds((const __attribute__((address_space(1))) void*)g,
                                   (__attribute__((address_space(3))) void*)l, 16, 0, 0);
}

// ---- shared staging (64B rows, sw4 XOR), R3-verified ----
template<int NR>
__device__ __forceinline__ void stage(f16* lds, const f16* src, int ldk, int k0, int tid){
  #pragma unroll
  for (int ic=0; ic<NR/64; ++ic){
    const int c = tid + ic*256;
    const int row = c>>2, c4 = c&3;
    const f16* g = src + (long)row*ldk + k0 + ((c4 ^ sw4(row))<<3);
    gld(g, lds + c*8);
  }
}
__device__ __forceinline__ f16x8 fragI(const f16* lds, int row, int rq){
  return *(const f16x8*)&lds[row*32 + ((rq ^ sw4(row))<<3)];
}
__device__ __forceinline__ f16x8 fragN(const f16* lds, int row, int lk){
  const int s = sw4(row);
  const int cl = (lk>>3) ^ s, ch = (2|(lk>>3)) ^ s;
  f16x4 lo = *(const f16x4*)&lds[row*32 + (cl<<3) + (lk&7)];
  f16x4 hi = *(const f16x4*)&lds[row*32 + (ch<<3) + (lk&7)];
  f16x8 r; r[0]=lo[0];r[1]=lo[1];r[2]=lo[2];r[3]=lo[3];
  r[4]=hi[0];r[5]=hi[1];r[6]=hi[2];r[7]=hi[3];
  return r;
}

// ---------------------------------------------------------------- diffusion GEMM (128x128, ring-4 pipelined, 256 thr)
// D[(q,n)][bu] = sum_m W[(q,n)][m] * Y[bu][m]; both operands ilv rows [.][1024].
struct DiffP {
  const f16* W; const f16* Y0; const f16* Y1;
  f16* out0; f16* out1;
  int nct0; int mode_x; int wsq;
};

__global__ __launch_bounds__(256) void gemm_diff(DiffP p) {
  __shared__ f16 L[4][8192];                // ring slot: W 128x32 at +0, Y 128x32 at +4096
  const int tid=threadIdx.x, l=tid&63, w=tid>>6;
  const int ro=l&15, rq=l>>4;
  const int rt = blockIdx.x, ct = blockIdx.y;   // natural order: XCD = rt%8 pins W panels
  const int part = (ct >= p.nct0) ? 1 : 0;
  const int ctl  = part ? ct - p.nct0 : ct;
  const f16* Wb = p.W + (long)rt*(128*1024);
  const f16* Yb = (part ? p.Y1 : p.Y0) + (long)ctl*(128*1024);
  const int wm=(w>>1)*64, wc=(w&1)*64;
  // staging: thread handles chunks tid and tid+256 (row = c>>2, chunk = c&3)
  const int ra=tid>>2, pa=tid&3, rb=(tid+256)>>2, pb2=tid&3;
  const long sa = (long)ra*1024 + ((pa ^ (ra&3))<<3);
  const long sb = (long)rb*1024 + ((pb2 ^ (rb&3))<<3);
  const int da = tid*8, db = (tid+256)*8;
  f32x4 acc[4][4] = {};
  auto STAGE = [&](int tt){
    f16* Lr = L[tt&3]; const int k0 = tt*32;
    gld(Wb+k0+sa, Lr+da);      gld(Wb+k0+sb, Lr+db);
    gld(Yb+k0+sa, Lr+4096+da); gld(Yb+k0+sb, Lr+4096+db);
  };
  STAGE(0); STAGE(1);
  asm volatile("s_waitcnt vmcnt(4)" ::: "memory");
  __builtin_amdgcn_s_barrier();
  __builtin_amdgcn_sched_barrier(0);
  for (int t=0; t<32; ++t) {
    const f16* Lw = L[t&3];
    const f16* Ly = Lw + 4096;
    if (t+2 < 32) STAGE(t+2);
    f16x8 b[4];
    #pragma unroll
    for (int j=0;j<4;j++){ const int r=wc+j*16+ro; b[j]=*(const f16x8*)&Ly[r*32+((rq^(r&3))<<3)]; }
    __builtin_amdgcn_s_setprio(1);
    if (!p.wsq) {
      #pragma unroll
      for (int i=0;i<4;i++){
        const int r=wm+i*16+ro;
        const f16x8 a = *(const f16x8*)&Lw[r*32+((rq^(r&3))<<3)];
        #pragma unroll
        for (int j=0;j<4;j++)
          acc[i][j]=__builtin_amdgcn_mfma_f32_16x16x32_f16(a,b[j],acc[i][j],0,0,0);
      }
    } else {
      #pragma unroll
      for (int i=0;i<4;i++){
        const int r=wm+i*16+ro;
        const f16x8 a = *(const f16x8*)&Lw[r*32+((rq^(r&3))<<3)];
        #pragma unroll
        for (int j=0;j<4;j++)
          acc[i][j]=__builtin_amdgcn_mfma_f32_16x16x32_f16(b[j],a,acc[i][j],0,0,0);
      }
    }
    __builtin_amdgcn_s_setprio(0);
    if (t==31) break;
    if (t<29) { asm volatile("s_waitcnt vmcnt(4)" ::: "memory"); }
    else      { asm volatile("s_waitcnt vmcnt(0)" ::: "memory"); }
    __builtin_amdgcn_s_barrier();
    __builtin_amdgcn_sched_barrier(0);
  }
  if (p.wsq) {
    #pragma unroll
    for (int i=0;i<4;i++){
      const int n = rt*128 + wm + i*16 + ro;
      #pragma unroll
      for (int j=0;j<4;j++){
        const int m0 = ct*128 + wc + j*16 + rq*4;
        f16x4 sv;
        #pragma unroll
        for (int e=0;e<4;e++) sv[e] = (f16)(2.f*acc[i][j][e] - ((n==m0+e)?1.f:0.f));
        *(f16x4*)&p.out0[(long)n*1024 + m0] = sv;
      }
    }
    return;
  }
  f16* ob = part ? p.out1 : p.out0;
  const int mode = part ? p.mode_x : 0;
  #pragma unroll
  for (int i=0;i<4;i++){
    #pragma unroll
    for (int e=0;e<4;e++){
      const int c = rt*128 + wm + i*16 + rq*4 + e;   // global (q,n)
      const int q = c>>10, nn = c&1023;
      #pragma unroll
      for (int j=0;j<4;j++){
        const f16 v = (f16)acc[i][j][e];
        if (mode==0) {
          ob[(long)q*SLOT + (long)nn*4096 + (long)ctl*128 + wc + j*16 + ro] = v;
        } else {
          const int bul = wc + j*16 + ro;
          if (bul < 64) ob[(long)q*ROWS + nn*64 + bul] = v;
        }
      }
    }
  }
}

// ---------------------------------------------------------------- cell GEMMs (single-buffered)
struct Tab5 { const f16* p[5]; };
struct CellP {
  Tab5 ta, tb, xq;
  const f16 *wa, *wb, *wx0;   // wa/wb: [O][320] ilv; wx0: [5][O] natural
  const float* bias;
  const float* h32in;
  f16* rh; f16* rhhat; float* u32;
  float* h32io; f16* h16io; f16* hhat;
  int nseg, xf1;
};

template<int O, int GATE>
__global__ __launch_bounds__(256) void cell_gemm(CellP p) {
  constexpr int FC = O/32;
  __shared__ f16 As[128*32];
  __shared__ f16 Bs[O*32];
  const int tid=threadIdx.x, l=tid&63, w=tid>>6;
  const int rq=l>>4, ro=l&15, lk=rq*4;
  const int wm=(w>>1)*64, wc=(w&1)*(O/2);
  f32x4 acc[4][FC] = {};
  const long r0 = (long)blockIdx.x*128;
  const int Ktot = p.nseg*320;
  for (int kg=0; kg<Ktot; kg+=32) {
    const int seg = (kg>=320) ? 1 : 0;
    const int kk  = kg - seg*320;
    const int q = kk>>6, kq = kk&63;
    const f16* asrc = (seg ? p.tb.p[q] : p.ta.p[q]) + r0*64;
    const f16* wsrc = seg ? p.wb : p.wa;
    stage<128>(As, asrc, 64, kq, tid);
    stage<O>(Bs, wsrc, 320, kk, tid);
    __syncthreads();
    f16x8 a[4], b[FC];
    #pragma unroll
    for (int i=0;i<4;i++) a[i] = fragN(As, wm + i*16 + ro, lk);
    #pragma unroll
    for (int j=0;j<FC;j++) b[j] = fragI(Bs, wc + j*16 + ro, rq);
    #pragma unroll
    for (int i=0;i<4;i++)
      #pragma unroll
      for (int j=0;j<FC;j++)
        acc[i][j] = __builtin_amdgcn_mfma_f32_16x16x32_f16(a[i], b[j], acc[i][j], 0,0,0);
    __syncthreads();
  }
  #pragma unroll
  for (int i=0;i<4;i++) {
    #pragma unroll
    for (int e=0;e<4;e++) {
      const long rg = r0 + wm + i*16 + rq*4 + e;
      const int bb = (int)(rg & 63), nn2 = (int)(rg >> 6);
      const long hcol = (long)ilvpos(nn2);
      float xv[5];
      if (p.xf1) {
        #pragma unroll
        for (int q2=0;q2<5;q2++) xv[q2] = (float)p.xq.p[q2][rg];
      }
      #pragma unroll
      for (int j=0;j<FC;j++) {
        const int col = wc + j*16 + ro;
        float v = acc[i][j][e] + p.bias[col];
        if (p.xf1) {
          #pragma unroll
          for (int q2=0;q2<5;q2++) v += xv[q2] * (float)p.wx0[q2*O + col];
        }
        if (GATE) {
          const float s = 1.f/(1.f + __expf(-v));
          if (col < 64) {
            const float rhv = s * p.h32in[rg*64 + col];
            p.rh[rg*64 + col] = (f16)rhv;
            p.rhhat[((long)bb*64 + col)*1024 + hcol] = (f16)rhv;
          } else {
            p.u32[rg*64 + (col-64)] = s;
          }
        } else {
          const float cc = tanhf(v);
          const float u  = p.u32[rg*64 + col];
          const float h  = p.h32io[rg*64 + col];
          const float hn = u*h + (1.f-u)*cc;
          p.h32io[rg*64 + col] = hn;
          p.h16io[rg*64 + col] = (f16)hn;
          p.hhat[((long)bb*64 + col)*1024 + hcol] = (f16)hn;
        }
      }
    }
  }
}

// ---------------------------------------------------------------- setup kernels
__global__ __launch_bounds__(256) void k_transpose(const f16* in, f16* out, int R, int C) {
  __shared__ f16 T[64*66];
  const long rb = (long)blockIdx.x*64, cb = (long)blockIdx.y*64;
  const int t = threadIdx.x;
  #pragma unroll
  for (int it=0; it<2; ++it) {
    const int r = (t>>3) + it*32, c8 = (t&7)*8;
    f16x8 v = *(const f16x8*)(in + (rb+r)*C + cb + c8);
    *(f16x8*)&T[r*66 + c8] = v;
  }
  __syncthreads();
  #pragma unroll
  for (int it=0; it<2; ++it) {
    const int c = (t>>3) + it*32, r8 = (t&7)*8;
    f16x8 v;
    #pragma unroll
    for (int j=0;j<8;j++) v[j] = T[(r8+j)*66 + c];
    *(f16x8*)(out + (cb+c)*R + rb + r8) = v;
  }
}

__global__ void k_cast_sup(const float* s, f16* o) {
  long i = (long)blockIdx.x*256 + threadIdx.x;
  if (i < 2LL*MATH) o[i] = (f16)s[i];
}

__global__ void k_ilv(const f16* in, f16* out) {
  int i = blockIdx.x*256 + threadIdx.x;
  if (i >= MATH) return;
  int r = i>>10, k = i&1023;
  out[(long)r*1024 + ilvpos(k)] = in[i];
}

__global__ void k_pack_x(const float* in, f16* xe, f16* xet) {
  int i = blockIdx.x*256 + threadIdx.x;
  if (i >= NT*ROWS) return;
  int t = i / ROWS, r = i % ROWS, n = r>>6, b = r&63;
  float v = in[(long)b*NN*NT + (long)n*NT + t];
  xe[i] = (f16)v;
  xet[(long)t*262144 + (long)b*1024 + ilvpos(n)] = (f16)v;
}

__global__ void k_split_w_t(const float* src, f16* wh_t, f16* wxA, int f, int xf, int O) {
  int i = blockIdx.x*256 + threadIdx.x;
  if (i >= 5*f*O) return;
  int o = i % O, rr = i / O, q = rr / f, ff = rr % f;
  f16 v = (f16)src[i];
  if (ff < xf) {
    if (xf == 1) wxA[q*O + o] = v;
    else         wxA[(long)o*320 + q*64 + ilvpos(ff)] = v;
  } else {
    wh_t[(long)o*320 + q*64 + ilvpos(ff - xf)] = v;
  }
}

__global__ void k_proj(const float* h32, const float* pw, const float* pb,
                       float* out, f16* xdec, f16* xdect) {
  int r = blockIdx.x*256 + threadIdx.x;
  if (r >= ROWS) return;
  float acc = pb[0];
  const float* hp = h32 + (long)r*64;
  #pragma unroll
  for (int k=0;k<64;k++) acc += hp[k]*pw[k];
  int n = r>>6, b = r&63;
  out[(long)b*NN + n] = acc;
  xdec[r] = (f16)acc;
  xdect[(long)b*1024 + ilvpos(n)] = (f16)acc;
}

// ---------------------------------------------------------------- driver
extern "C" void kernel_launch(void* const* d_in, const int* in_sizes, int n_in,
                              void* d_out, int out_size, void* d_ws, size_t ws_size,
                              hipStream_t stream) {
  (void)in_sizes; (void)n_in; (void)out_size; (void)ws_size;
  const float* inputs = (const float*)d_in[0];
  const float* sup    = (const float*)d_in[1];
  const float* gwp[4] = {(const float*)d_in[2], (const float*)d_in[6], (const float*)d_in[10], (const float*)d_in[14]};
  const float* gbp[4] = {(const float*)d_in[3], (const float*)d_in[7], (const float*)d_in[11], (const float*)d_in[15]};
  const float* cwp[4] = {(const float*)d_in[4], (const float*)d_in[8], (const float*)d_in[12], (const float*)d_in[16]};
  const float* cbp[4] = {(const float*)d_in[5], (const float*)d_in[9], (const float*)d_in[13], (const float*)d_in[17]};
  const float* pw = (const float*)d_in[18];
  const float* pb = (const float*)d_in[19];
  float* out = (float*)d_out;

  char* base = (char*)d_ws; size_t off = 0;
  auto alloc = [&](size_t bytes)->void* { void* p = base + off; off += (bytes + 255) & ~(size_t)255; return p; };
  f16* W16int = (f16*)alloc(4LL*MATH*2);         // [A0, 2A0^2-I, A1, 2A1^2-I] ilv rows
  f16* xenc   = (f16*)alloc((long)NT*ROWS*2);
  f16* xet    = (f16*)alloc((long)NT*262144*2);  // [t][256 row-pad][1024 n-ilv]
  f16* xdec   = (f16*)alloc((long)ROWS*2);
  f16* xdect  = (f16*)alloc(262144L*2);
  f16*  h16[2]  = {(f16*)alloc((long)ROWS*64*2),  (f16*)alloc((long)ROWS*64*2)};
  f16*  hh[2]   = {(f16*)alloc(4096L*1024*2),     (f16*)alloc(4096L*1024*2)};
  float* h32[2] = {(float*)alloc((long)ROWS*64*4), (float*)alloc((long)ROWS*64*4)};
  float* u32 = (float*)alloc((long)ROWS*64*4);
  f16* rh    = (f16*)alloc((long)ROWS*64*2);
  f16* rhh   = (f16*)alloc(4096L*1024*2);
  f16* Dh    = (f16*)alloc(4*SLOT*2);
  f16* Dx    = (f16*)alloc(4*SLOT*2);
  f16* Dx0   = (f16*)alloc(4LL*ROWS*2);
  f16 *gwh[4], *gwx[4], *cwh[4], *cwx[4];
  for (int i=0;i<4;i++) {
    gwh[i]=(f16*)alloc(128L*320*2); gwx[i]=(f16*)alloc(128L*320*2);
    cwh[i]=(f16*)alloc(64L*320*2);  cwx[i]=(f16*)alloc(64L*320*2);
  }

  hipMemsetAsync(h16[0], 0, (long)ROWS*64*2, stream);
  hipMemsetAsync(h16[1], 0, (long)ROWS*64*2, stream);
  hipMemsetAsync(hh[0],  0, 4096L*1024*2, stream);
  hipMemsetAsync(hh[1],  0, 4096L*1024*2, stream);
  hipMemsetAsync(h32[0], 0, (long)ROWS*64*4, stream);
  hipMemsetAsync(h32[1], 0, (long)ROWS*64*4, stream);
  hipMemsetAsync(xdec,   0, (long)ROWS*2, stream);
  hipMemsetAsync(xdect,  0, 262144L*2, stream);
  hipMemsetAsync(xet,    0, (long)NT*262144*2, stream);

  // setup: W16int[2s] = ilv(A_s); W16int[2s+1] = ilv(2*A_s^2 - I)
  f16* tmpA   = Dh;
  f16* tmpAt  = Dh + 2L*MATH;
  f16* tmpAti = Dh + 4L*MATH;
  f16* tmpSq  = Dh + 5L*MATH;
  k_cast_sup<<<(2*MATH+255)/256, 256, 0, stream>>>(sup, tmpA);
  for (int s=0;s<2;s++) {
    k_transpose<<<dim3(16,16),256,0,stream>>>(tmpA + (long)s*MATH, tmpAt + (long)s*MATH, 1024, 1024);
    k_ilv<<<4096,256,0,stream>>>(tmpA + (long)s*MATH, W16int + (long)(2*s)*MATH);
  }
  for (int s=0;s<2;s++) {
    k_ilv<<<4096,256,0,stream>>>(tmpAt + (long)s*MATH, tmpAti);
    DiffP mp{};
    mp.W = W16int + (long)(2*s)*MATH; mp.Y0 = tmpAti; mp.Y1 = tmpAti;
    mp.out0 = tmpSq; mp.nct0 = 8; mp.wsq = 1;
    gemm_diff<<<dim3(8,8),256,0,stream>>>(mp);
    k_ilv<<<4096,256,0,stream>>>(tmpSq, W16int + (long)(2*s+1)*MATH);
  }
  k_pack_x<<<(NT*ROWS+255)/256,256,0,stream>>>(inputs, xenc, xet);
  const int fs[4]  = {65,128,65,128};
  const int xfs[4] = {1,64,1,64};
  for (int i=0;i<4;i++) {
    k_split_w_t<<<(5*fs[i]*128+255)/256,256,0,stream>>>(gwp[i], gwh[i], gwx[i], fs[i], xfs[i], 128);
    k_split_w_t<<<(5*fs[i]*64 +255)/256,256,0,stream>>>(cwp[i], cwh[i], cwx[i], fs[i], xfs[i], 64);
  }

  auto run_cell = [&](const f16* xraw, const f16* xhat, int xf,
                      f16* h16c, f16* hhatc, float* h32c, int wi) {
    // diffusion of h (+x)
    DiffP dp{};
    dp.W = W16int; dp.Y0 = hhatc; dp.out0 = Dh; dp.nct0 = 32; dp.wsq = 0;
    int gy;
    if (xf == 64) { dp.Y1 = xhat; dp.out1 = Dx;  dp.mode_x = 0; gy = 64; }
    else          { dp.Y1 = xhat; dp.out1 = Dx0; dp.mode_x = 2; gy = 33; }
    gemm_diff<<<dim3(32, gy), 256, 0, stream>>>(dp);
    // gate
    CellP gp{};
    gp.ta.p[0] = h16c; for (int q=1;q<5;q++) gp.ta.p[q] = Dh + (long)(q-1)*SLOT;
    gp.wa = gwh[wi]; gp.bias = gbp[wi];
    gp.h32in = h32c; gp.rh = rh; gp.rhhat = rhh; gp.u32 = u32;
    if (xf == 64) {
      gp.nseg = 2; gp.xf1 = 0;
      gp.tb.p[0] = xraw; for (int q=1;q<5;q++) gp.tb.p[q] = Dx + (long)(q-1)*SLOT;
      gp.wb = gwx[wi];
    } else {
      gp.nseg = 1; gp.xf1 = 1;
      gp.xq.p[0] = xraw; for (int q=1;q<5;q++) gp.xq.p[q] = Dx0 + (long)(q-1)*ROWS;
      gp.wx0 = gwx[wi];
    }
    cell_gemm<128,1><<<512, 256, 0, stream>>>(gp);
    // diffusion of rh
    DiffP dp2{};
    dp2.W = W16int; dp2.Y0 = rhh; dp2.Y1 = rhh; dp2.out0 = Dh; dp2.nct0 = 32; dp2.wsq = 0;
    gemm_diff<<<dim3(32, 32), 256, 0, stream>>>(dp2);
    // candidate + GRU update
    CellP cp{};
    cp.ta.p[0] = rh; for (int q=1;q<5;q++) cp.ta.p[q] = Dh + (long)(q-1)*SLOT;
    cp.wa = cwh[wi]; cp.bias = cbp[wi];
    cp.u32 = u32; cp.h32io = h32c; cp.h16io = h16c; cp.hhat = hhatc;
    if (xf == 64) {
      cp.nseg = 2; cp.xf1 = 0;
      cp.tb.p[0] = xraw; for (int q=1;q<5;q++) cp.tb.p[q] = Dx + (long)(q-1)*SLOT;
      cp.wb = cwx[wi];
    } else {
      cp.nseg = 1; cp.xf1 = 1;
      cp.xq.p[0] = xraw; for (int q=1;q<5;q++) cp.xq.p[q] = Dx0 + (long)(q-1)*ROWS;
      cp.wx0 = cwx[wi];
    }
    cell_gemm<64,0><<<512, 256, 0, stream>>>(cp);
  };

  for (int t=0;t<NT;t++) {
    run_cell(xenc + (long)t*ROWS, xet + (long)t*262144, 1, h16[0], hh[0], h32[0], 0);
    run_cell(h16[0], hh[0],                            64, h16[1], hh[1], h32[1], 1);
  }
  for (int s=0;s<NHOR;s++) {
    run_cell(xdec,   xdect,   1, h16[0], hh[0], h32[0], 2);
    run_cell(h16[0], hh[0],  64, h16[1], hh[1], h32[1], 3);
    k_proj<<<ROWS/256, 256, 0, stream>>>(h32[1], pw, pb, out + (long)s*ROWS, xdec, xdect);
  }
}